// Round 1
// baseline (3014.989 us; speedup 1.0000x reference)
//
#include <hip/hip_runtime.h>

// ---------------------------------------------------------------------------
// MultiDetector (SSD-style 3D conv pyramid) — round 1: correct fp32 GEMMs.
//  * H=W=2 -> fold (h,w) into channels; convs become GEMMs.
//  * e*_w2: stride2+dilation2 in D -> only EVEN input slices consumed ->
//    pointwise e*_w1 computed on even slices only (half the work).
//  * Activations channel-last [b][d][hw][c] so GEMM K is contiguous.
// ---------------------------------------------------------------------------

// ---------------- pointwise (1x1x1) conv as GEMM -----------------
// out[m*N+n] = sum_k A[base(m) + k*sK] * W[n*K + k]
// m = b*2^lgRows + dd*4 + hw ; base = b*sB + dd*sD + hw*sHW  (dd = even-d idx)
template<int BM, int BN, int KS, int TM, int TN, bool XLAY>
__global__ __launch_bounds__(256)
void gemm_pw(const float* __restrict__ A, const float* __restrict__ W,
             float* __restrict__ out, const int N, const int K,
             const int sB, const int sD, const int sHW, const int sK,
             const int lgRows)
{
  constexpr int PAD = 4;
  __shared__ __align__(16) float As[KS][BM + PAD];
  __shared__ __align__(16) float Bs[KS][BN + PAD];
  const int tid = threadIdx.x;
  const int bm = blockIdx.x, bn = blockIdx.y;

  const int kkB = tid % KS;
  const int lB  = tid / KS;
  constexpr int RPC = 256 / KS;
  constexpr int AJ = BM * KS / 256;
  constexpr int BJ = BN * KS / 256;

  int aRow[XLAY ? 1 : AJ];
  int aKb = 0, aM = 0;
  if constexpr (XLAY) {
    aM  = tid % BM;
    aKb = tid / BM;
    const int m = bm * BM + aM;
    const int b = m >> lgRows, r = m & ((1 << lgRows) - 1);
    aRow[0] = b * sB + (r >> 2) * sD + (r & 3) * sHW;
  } else {
    #pragma unroll
    for (int j = 0; j < AJ; ++j) {
      const int m = bm * BM + lB + j * RPC;
      const int b = m >> lgRows, r = m & ((1 << lgRows) - 1);
      aRow[j] = b * sB + (r >> 2) * sD + (r & 3) * sHW;
    }
  }

  const int tx = tid % (BN / TN), ty = tid / (BN / TN);
  float acc[TM][TN] = {};

  for (int k0 = 0; k0 < K; k0 += KS) {
    if constexpr (XLAY) {
      constexpr int KPC = 256 / BM;
      #pragma unroll
      for (int j = 0; j < KS / KPC; ++j) {
        const int kk = aKb + j * KPC;
        As[kk][aM] = A[aRow[0] + (k0 + kk) * sK];
      }
    } else {
      #pragma unroll
      for (int j = 0; j < AJ; ++j)
        As[kkB][lB + j * RPC] = A[aRow[j] + (k0 + kkB) * sK];
    }
    #pragma unroll
    for (int j = 0; j < BJ; ++j) {
      const int n = bn * BN + lB + j * RPC;
      Bs[kkB][lB + j * RPC] = W[n * K + k0 + kkB];
    }
    __syncthreads();
    #pragma unroll
    for (int q = 0; q < KS; ++q) {
      float a[TM], bv[TN];
      #pragma unroll
      for (int i = 0; i < TM; i += 4)
        *reinterpret_cast<float4*>(&a[i]) =
            *reinterpret_cast<const float4*>(&As[q][ty * TM + i]);
      #pragma unroll
      for (int j = 0; j < TN; j += 4)
        *reinterpret_cast<float4*>(&bv[j]) =
            *reinterpret_cast<const float4*>(&Bs[q][tx * TN + j]);
      #pragma unroll
      for (int i = 0; i < TM; ++i)
        #pragma unroll
        for (int j = 0; j < TN; ++j)
          acc[i][j] += a[i] * bv[j];
    }
    __syncthreads();
  }

  #pragma unroll
  for (int i = 0; i < TM; ++i) {
    const int m = bm * BM + ty * TM + i;
    #pragma unroll
    for (int j = 0; j < TN; j += 4) {
      float4 v;
      v.x = acc[i][j]; v.y = acc[i][j + 1]; v.z = acc[i][j + 2]; v.w = acc[i][j + 3];
      *reinterpret_cast<float4*>(&out[(size_t)m * N + bn * BN + tx * TN + j]) = v;
    }
  }
}

// ------------- dilated 3x3x3 conv (stride2/dil2 in D) as folded GEMM -------
// m = b*Dout + d' ; n = hw'*cout + o ; k = kd*(4*cin) + hw*cin + c
// A[m,k] = in[b][d'-1+kd][hw][c] (0 if D-tap out of range)
// B[k,n] = w2[o][c][kd][1+h-h'][1+w-w']
template<int BM, int BN, int KS, int TM, int TN>
__global__ __launch_bounds__(256)
void gemm_dil(const float* __restrict__ A, const float* __restrict__ W2,
              float* __restrict__ out, const int N, const int K,
              const int lgD, const int lgCin, const int lgCout)
{
  constexpr int PAD = 4;
  __shared__ __align__(16) float As[KS][BM + PAD];
  __shared__ __align__(16) float Bs[KS][BN + PAD];
  const int tid = threadIdx.x;
  const int bm = blockIdx.x, bn = blockIdx.y;
  const int kkB = tid % KS;
  const int lB  = tid / KS;
  constexpr int RPC = 256 / KS;
  constexpr int AJ = BM * KS / 256;
  constexpr int BJ = BN * KS / 256;

  int aBD[AJ], aD[AJ];
  #pragma unroll
  for (int j = 0; j < AJ; ++j) {
    const int m = bm * BM + lB + j * RPC;
    const int b = m >> lgD;
    aD[j]  = m & ((1 << lgD) - 1);
    aBD[j] = b << lgD;   // b * Dhalf
  }
  int nHW[BJ], nO[BJ];
  #pragma unroll
  for (int j = 0; j < BJ; ++j) {
    const int n = bn * BN + lB + j * RPC;
    nHW[j] = n >> lgCout;
    nO[j]  = n & ((1 << lgCout) - 1);
  }

  const int tx = tid % (BN / TN), ty = tid / (BN / TN);
  float acc[TM][TN] = {};

  for (int k0 = 0; k0 < K; k0 += KS) {
    const int k   = k0 + kkB;
    const int kd  = k >> (lgCin + 2);
    const int rem = k & ((4 << lgCin) - 1);
    const int hw  = rem >> lgCin;
    const int c   = rem & ((1 << lgCin) - 1);
    #pragma unroll
    for (int j = 0; j < AJ; ++j) {
      const int din = aD[j] - 1 + kd;
      float v = 0.f;
      if ((unsigned)din < (unsigned)(1 << lgD))
        v = A[((((aBD[j] + din) << 2) + hw) << lgCin) + c];
      As[kkB][lB + j * RPC] = v;
    }
    const int h = hw >> 1, w = hw & 1;
    #pragma unroll
    for (int j = 0; j < BJ; ++j) {
      const int kh = 1 + h - (nHW[j] >> 1);
      const int kw = 1 + w - (nHW[j] & 1);
      Bs[kkB][lB + j * RPC] =
          W2[(((nO[j] << lgCin) + c) * 27) + kd * 9 + kh * 3 + kw];
    }
    __syncthreads();
    #pragma unroll
    for (int q = 0; q < KS; ++q) {
      float a[TM], bv[TN];
      #pragma unroll
      for (int i = 0; i < TM; i += 4)
        *reinterpret_cast<float4*>(&a[i]) =
            *reinterpret_cast<const float4*>(&As[q][ty * TM + i]);
      #pragma unroll
      for (int j = 0; j < TN; j += 4)
        *reinterpret_cast<float4*>(&bv[j]) =
            *reinterpret_cast<const float4*>(&Bs[q][tx * TN + j]);
      #pragma unroll
      for (int i = 0; i < TM; ++i)
        #pragma unroll
        for (int j = 0; j < TN; ++j)
          acc[i][j] += a[i] * bv[j];
    }
    __syncthreads();
  }

  #pragma unroll
  for (int i = 0; i < TM; ++i) {
    const int m = bm * BM + ty * TM + i;
    #pragma unroll
    for (int j = 0; j < TN; j += 4) {
      float4 v;
      v.x = acc[i][j]; v.y = acc[i][j + 1]; v.z = acc[i][j + 2]; v.w = acc[i][j + 3];
      *reinterpret_cast<float4*>(&out[(size_t)m * N + bn * BN + tx * TN + j]) = v;
    }
  }
}

// ---------------- detection heads: kernel (2,2,2), VALID -------------------
// One block per (b, d). 2 loc + 3 conf dot-products of length C*8, reduced
// across 256 threads.
template<bool XL>   // XL: input is x in NCDHW (c-stride sC); else channel-last
__global__ __launch_bounds__(256)
void heads_kernel(const float* __restrict__ in, const float* __restrict__ wl,
                  const float* __restrict__ wc, float* __restrict__ out,
                  const int C, const int dcnt, const int sB, const int sD,
                  const int sHW, const int sC, const int loff, const int coff)
{
  const int tid = threadIdx.x;
  const int blk = blockIdx.x;
  const int b = blk / dcnt, d = blk - b * dcnt;
  float a0 = 0, a1 = 0, c0 = 0, c1 = 0, c2 = 0;
  const int C8 = C * 8;
  if constexpr (XL) {
    const int hw = tid & 3, kd = (tid >> 2) & 1, cb = tid >> 3;
    const int base = b * sB + (d + kd) * sD + hw * sHW;
    const int wb = kd * 4 + hw;
    for (int i = 0; i < C / 32; ++i) {
      const int c = cb + i * 32;
      const float v = in[base + c * sC];
      const int wi = c * 8 + wb;
      a0 += v * wl[wi];           a1 += v * wl[C8 + wi];
      c0 += v * wc[wi];           c1 += v * wc[C8 + wi];
      c2 += v * wc[2 * C8 + wi];
    }
  } else {
    for (int c = tid; c < C; c += 256) {
      #pragma unroll
      for (int kd = 0; kd < 2; ++kd) {
        #pragma unroll
        for (int hw = 0; hw < 4; ++hw) {
          const float v = in[b * sB + (d + kd) * sD + hw * sHW + c];
          const int wi = c * 8 + kd * 4 + hw;
          a0 += v * wl[wi];           a1 += v * wl[C8 + wi];
          c0 += v * wc[wi];           c1 += v * wc[C8 + wi];
          c2 += v * wc[2 * C8 + wi];
        }
      }
    }
  }
  #pragma unroll
  for (int off = 32; off; off >>= 1) {
    a0 += __shfl_down(a0, off, 64);
    a1 += __shfl_down(a1, off, 64);
    c0 += __shfl_down(c0, off, 64);
    c1 += __shfl_down(c1, off, 64);
    c2 += __shfl_down(c2, off, 64);
  }
  __shared__ float red[5][4];
  const int lane = tid & 63, wv = tid >> 6;
  if (lane == 0) {
    red[0][wv] = a0; red[1][wv] = a1; red[2][wv] = c0; red[3][wv] = c1; red[4][wv] = c2;
  }
  __syncthreads();
  if (tid == 0) {
    float L0 = red[0][0] + red[0][1] + red[0][2] + red[0][3];
    float L1 = red[1][0] + red[1][1] + red[1][2] + red[1][3];
    float F0 = red[2][0] + red[2][1] + red[2][2] + red[2][3];
    float F1 = red[3][0] + red[3][1] + red[3][2] + red[3][3];
    float F2 = red[4][0] + red[4][1] + red[4][2] + red[4][3];
    float* loc = out + (size_t)b * 52 + loff;
    loc[0 * dcnt + d] = L0;
    loc[1 * dcnt + d] = L1;
    float* cf = out + 6656 + (size_t)b * 78 + coff;   // 128*52 = 6656
    cf[0 * dcnt + d] = F0;
    cf[1 * dcnt + d] = F1;
    cf[2 * dcnt + d] = F2;
  }
}

extern "C" void kernel_launch(void* const* d_in, const int* in_sizes, int n_in,
                              void* d_out, int out_size, void* d_ws, size_t ws_size,
                              hipStream_t stream) {
  (void)in_sizes; (void)n_in; (void)out_size; (void)ws_size;
  const float* x    = (const float*)d_in[0];
  const float* lw0  = (const float*)d_in[2];
  const float* cw0  = (const float*)d_in[3];
  const float* e0w1 = (const float*)d_in[4];
  const float* e0w2 = (const float*)d_in[5];
  const float* lw1  = (const float*)d_in[6];
  const float* cw1  = (const float*)d_in[7];
  const float* e1w1 = (const float*)d_in[8];
  const float* e1w2 = (const float*)d_in[9];
  const float* lw2  = (const float*)d_in[10];
  const float* cw2  = (const float*)d_in[11];
  const float* e2w1 = (const float*)d_in[12];
  const float* e2w2 = (const float*)d_in[13];
  const float* lw3  = (const float*)d_in[14];
  const float* cw3  = (const float*)d_in[15];
  float* out = (float*)d_out;
  float* ws  = (float*)d_ws;
  float* h1a = ws;                  // [128][8 even-d][4][512]
  float* h1b = h1a + 2097152;       // [128][8][4][1024]
  float* h2a = h1b + 4194304;       // [128][4 even-d][4][256]
  float* h2b = h2a + 524288;        // [128][4][4][512]
  float* h3a = h2b + 1048576;       // [128][2 even-d][4][128]
  float* h3b = h3a + 131072;        // [128][2][4][256]

  // e0_w1 on even d of x (NCDHW: sB=2048*64, dd step=8, hw=1, k-stride=64)
  gemm_pw<64, 64, 32, 4, 4, true><<<dim3(64, 8), 256, 0, stream>>>(
      x, e0w1, h1a, 512, 2048, 131072, 8, 1, 64, 5);
  // e0_w2: M=1024, N=4096, K=6144
  gemm_dil<128, 128, 16, 8, 8><<<dim3(8, 32), 256, 0, stream>>>(
      h1a, e0w2, h1b, 4096, 6144, 3, 9, 10);
  // e1_w1 on even d of h1b
  gemm_pw<64, 64, 32, 4, 4, false><<<dim3(32, 4), 256, 0, stream>>>(
      h1b, e1w1, h2a, 256, 1024, 32768, 8192, 1024, 1, 4);
  // e1_w2: M=512, N=2048, K=3072
  gemm_dil<64, 64, 32, 4, 4><<<dim3(8, 32), 256, 0, stream>>>(
      h2a, e1w2, h2b, 2048, 3072, 2, 8, 9);
  // e2_w1 on even d of h2b
  gemm_pw<64, 64, 32, 4, 4, false><<<dim3(16, 2), 256, 0, stream>>>(
      h2b, e2w1, h3a, 128, 512, 8192, 4096, 512, 1, 3);
  // e2_w2: M=256, N=1024, K=1536
  gemm_dil<64, 64, 32, 4, 4><<<dim3(4, 16), 256, 0, stream>>>(
      h3a, e2w2, h3b, 1024, 1536, 1, 7, 8);

  // heads
  heads_kernel<true><<<128 * 15, 256, 0, stream>>>(
      x, lw0, cw0, out, 2048, 15, 131072, 4, 1, 64, 0, 0);
  heads_kernel<false><<<128 * 7, 256, 0, stream>>>(
      h1b, lw1, cw1, out, 1024, 7, 32768, 4096, 1024, 1, 30, 45);
  heads_kernel<false><<<128 * 3, 256, 0, stream>>>(
      h2b, lw2, cw2, out, 512, 3, 8192, 2048, 512, 1, 44, 66);
  heads_kernel<false><<<128 * 1, 256, 0, stream>>>(
      h3b, lw3, cw3, out, 256, 1, 2048, 1024, 256, 1, 50, 75);
}

// Round 3
// 379.626 us; speedup vs baseline: 7.9420x; 7.9420x over previous
//
#include <hip/hip_runtime.h>

typedef __bf16 bf16;
typedef bf16 bf16x2 __attribute__((ext_vector_type(2)));
typedef bf16 bf16x8 __attribute__((ext_vector_type(8)));
typedef float f32x4 __attribute__((ext_vector_type(4)));

__device__ __forceinline__ void gload16(const bf16* g, bf16* l) {
  __builtin_amdgcn_global_load_lds((const __attribute__((address_space(1))) void*)g,
                                   (__attribute__((address_space(3))) void*)l, 16, 0, 0);
}

// ---------- pack x [128][2048][16][4] f32 -> A0 bf16 [4096][2048] (even d) ----------
__global__ __launch_bounds__(256) void pack_x(const float* __restrict__ x, bf16* __restrict__ A0) {
  __shared__ float tile[64 * 65];
  const int b = blockIdx.x, cb = blockIdx.y;
  const int t = threadIdx.x;
  const float* src = x + ((size_t)b * 2048 + cb * 64) * 64;
  #pragma unroll
  for (int p = 0; p < 16; ++p) {
    int idx = t + p * 256;
    int cl = idx >> 6, dhw = idx & 63;
    tile[cl * 65 + dhw] = src[idx];
  }
  __syncthreads();
  bf16* dst = A0 + ((size_t)b * 32) * 2048 + cb * 64;
  const int cl2 = (t & 31) * 2, mr0 = t >> 5;
  #pragma unroll
  for (int p = 0; p < 4; ++p) {
    int mrow = mr0 + p * 8;
    int dd = mrow >> 2, hw = mrow & 3;
    int sdhw = dd * 8 + hw;
    bf16x2 v;
    v.x = (bf16)tile[cl2 * 65 + sdhw];
    v.y = (bf16)tile[(cl2 + 1) * 65 + sdhw];
    *(bf16x2*)(dst + (size_t)mrow * 2048 + cl2) = v;
  }
}

// ---------- f32 -> bf16 flat convert (n8 groups of 8) ----------
__global__ __launch_bounds__(256) void cvt_w1(const float* __restrict__ in, bf16* __restrict__ out, int n8) {
  int i = blockIdx.x * 256 + threadIdx.x;
  if (i < n8) {
    const float4* p = (const float4*)(in + (size_t)i * 8);
    float4 a = p[0], b = p[1];
    bf16x8 v = {(bf16)a.x, (bf16)a.y, (bf16)a.z, (bf16)a.w,
                (bf16)b.x, (bf16)b.y, (bf16)b.z, (bf16)b.w};
    *(bf16x8*)(out + (size_t)i * 8) = v;
  }
}

// ---------- w2 [cout][cin][27] f32 -> w2p [oCnt][27][cin] bf16 ----------
__global__ __launch_bounds__(256) void pack_w2(const float* __restrict__ w2, bf16* __restrict__ w2p,
                                               int oBase, int cin) {
  __shared__ float tile[64 * 27];
  const int orel = blockIdx.x, cb = blockIdx.y;
  const int o = oBase + orel;
  const float* src = w2 + ((size_t)o * cin + cb * 64) * 27;
  const int t = threadIdx.x;
  for (int idx = t; idx < 1728; idx += 256) tile[idx] = src[idx];
  __syncthreads();
  bf16* dst = w2p + (size_t)orel * 27 * cin + cb * 64;
  for (int idx = t; idx < 1728; idx += 256) {
    int tap = idx >> 6, cl = idx & 63;
    dst[(size_t)tap * cin + cl] = (bf16)tile[cl * 27 + tap];
  }
}

// ---------- bf16 MFMA GEMM ----------
struct GP {
  const bf16* A; const bf16* B; bf16* O;
  int K;
  int ashb, asB, am1, as1, am2, as2;                 // A row base decompose
  int oshb, osB, om1, os1, om2, os2, oOff;           // out row base decompose
  int lgCv, coutS, oCol0, lgCin;                     // out col map / w2p mode
};

template <int FM, int FN, bool W2M>
__global__ __launch_bounds__(256) void gemm_bf(GP p) {
  constexpr int BM = FM * 32, BN = FN * 32;
  __shared__ bf16 lds[(BM + BN) * 64];
  bf16* ldsA = lds;
  bf16* ldsB = lds + BM * 64;
  const int tid = threadIdx.x;
  const int bm = blockIdx.x, bn = blockIdx.y;

  int aBase[BM / 32], aL[BM / 32];
  #pragma unroll
  for (int q = 0; q < BM / 32; ++q) {
    int idx = tid + q * 256;
    int row = idx >> 3, cg = idx & 7;
    int m = bm * BM + row;
    aBase[q] = (m >> p.ashb) * p.asB + ((m >> 2) & p.am1) * p.as1 + (m & p.am2) * p.as2;
    aL[q] = (cg ^ (row & 7)) * 8;
  }
  int bN[BN / 32], bL[BN / 32];
  #pragma unroll
  for (int q = 0; q < BN / 32; ++q) {
    int idx = tid + q * 256;
    int row = idx >> 3, cg = idx & 7;
    bN[q] = bn * BN + row;
    bL[q] = (cg ^ (row & 7)) * 8;
  }

  const int wv = tid >> 6, wm = wv >> 1, wn = wv & 1;
  const int lane = tid & 63, r = lane & 15, g = lane >> 4;

  f32x4 acc[FM][FN];
  const f32x4 zz = {0.f, 0.f, 0.f, 0.f};
  #pragma unroll
  for (int i = 0; i < FM; ++i)
    #pragma unroll
    for (int j = 0; j < FN; ++j) acc[i][j] = zz;

  for (int k0 = 0; k0 < p.K; k0 += 64) {
    #pragma unroll
    for (int q = 0; q < BM / 32; ++q) {
      int idx = tid + q * 256;
      gload16(p.A + aBase[q] + k0 + aL[q], ldsA + idx * 8);
    }
    if (W2M) {
      const int kd = k0 >> (p.lgCin + 2);
      const int hw = (k0 >> p.lgCin) & 3;
      const int c0 = k0 & ((1 << p.lgCin) - 1);
      #pragma unroll
      for (int q = 0; q < BN / 32; ++q) {
        int n = bN[q];
        int op = n & ((1 << p.lgCv) - 1);
        int hwp = n >> p.lgCv;
        int kh = 1 + (hw >> 1) - (hwp >> 1);
        int kw = 1 + (hw & 1) - (hwp & 1);
        int src = ((op * 27 + kd * 9 + kh * 3 + kw) << p.lgCin) + c0 + bL[q];
        int idx = tid + q * 256;
        gload16(p.B + src, ldsB + idx * 8);
      }
    } else {
      #pragma unroll
      for (int q = 0; q < BN / 32; ++q) {
        int idx = tid + q * 256;
        gload16(p.B + (size_t)bN[q] * p.K + k0 + bL[q], ldsB + idx * 8);
      }
    }
    __syncthreads();
    #pragma unroll
    for (int ks = 0; ks < 2; ++ks) {
      bf16x8 af[FM], bfr[FN];
      #pragma unroll
      for (int i = 0; i < FM; ++i) {
        int row = wm * FM * 16 + i * 16 + r;
        int pcg = (ks * 4 + g) ^ (row & 7);
        af[i] = *(const bf16x8*)(ldsA + row * 64 + pcg * 8);
      }
      #pragma unroll
      for (int j = 0; j < FN; ++j) {
        int row = wn * FN * 16 + j * 16 + r;
        int pcg = (ks * 4 + g) ^ (row & 7);
        bfr[j] = *(const bf16x8*)(ldsB + row * 64 + pcg * 8);
      }
      #pragma unroll
      for (int i = 0; i < FM; ++i)
        #pragma unroll
        for (int j = 0; j < FN; ++j)
          acc[i][j] = __builtin_amdgcn_mfma_f32_16x16x32_bf16(af[i], bfr[j], acc[i][j], 0, 0, 0);
    }
    __syncthreads();
  }

  #pragma unroll
  for (int i = 0; i < FM; ++i) {
    #pragma unroll
    for (int j = 0; j < FN; ++j) {
      int ncol = bn * BN + wn * FN * 16 + j * 16 + r;
      int outcol = (ncol >> p.lgCv) * p.coutS + p.oCol0 + (ncol & ((1 << p.lgCv) - 1));
      #pragma unroll
      for (int jr = 0; jr < 4; ++jr) {
        int m = bm * BM + wm * FM * 16 + i * 16 + g * 4 + jr;
        int oa = (m >> p.oshb) * p.osB + ((m >> 2) & p.om1) * p.os1 + (m & p.om2) * p.os2 + p.oOff + outcol;
        p.O[oa] = (bf16)acc[i][j][jr];
      }
    }
  }
}

// ---------- detection heads: kernel (2,2,2) VALID ----------
template <typename T, bool XL>
__global__ __launch_bounds__(256)
void heads_k(const T* __restrict__ in, const float* __restrict__ wl,
             const float* __restrict__ wc, float* __restrict__ out,
             const int C, const int dcnt, const int sB, const int sD,
             const int sHW, const int sC, const int loff, const int coff) {
  const int tid = threadIdx.x;
  const int blk = blockIdx.x;
  const int b = blk / dcnt, d = blk - b * dcnt;
  float a0 = 0, a1 = 0, c0 = 0, c1 = 0, c2 = 0;
  const int C8 = C * 8;
  if constexpr (XL) {
    const int hw = tid & 3, kd = (tid >> 2) & 1, cb = tid >> 3;
    const int base = b * sB + (d + kd) * sD + hw * sHW;
    const int wb = kd * 4 + hw;
    for (int i = 0; i < C / 32; ++i) {
      const int c = cb + i * 32;
      const float v = (float)in[base + c * sC];
      const int wi = c * 8 + wb;
      a0 += v * wl[wi];  a1 += v * wl[C8 + wi];
      c0 += v * wc[wi];  c1 += v * wc[C8 + wi];  c2 += v * wc[2 * C8 + wi];
    }
  } else {
    for (int c = tid; c < C; c += 256) {
      #pragma unroll
      for (int kd = 0; kd < 2; ++kd) {
        #pragma unroll
        for (int hw = 0; hw < 4; ++hw) {
          const float v = (float)in[b * sB + (d + kd) * sD + hw * sHW + c];
          const int wi = c * 8 + kd * 4 + hw;
          a0 += v * wl[wi];  a1 += v * wl[C8 + wi];
          c0 += v * wc[wi];  c1 += v * wc[C8 + wi];  c2 += v * wc[2 * C8 + wi];
        }
      }
    }
  }
  #pragma unroll
  for (int off = 32; off; off >>= 1) {
    a0 += __shfl_down(a0, off, 64);
    a1 += __shfl_down(a1, off, 64);
    c0 += __shfl_down(c0, off, 64);
    c1 += __shfl_down(c1, off, 64);
    c2 += __shfl_down(c2, off, 64);
  }
  __shared__ float red[5][4];
  const int lane = tid & 63, wv = tid >> 6;
  if (lane == 0) { red[0][wv] = a0; red[1][wv] = a1; red[2][wv] = c0; red[3][wv] = c1; red[4][wv] = c2; }
  __syncthreads();
  if (tid == 0) {
    float L0 = red[0][0] + red[0][1] + red[0][2] + red[0][3];
    float L1 = red[1][0] + red[1][1] + red[1][2] + red[1][3];
    float F0 = red[2][0] + red[2][1] + red[2][2] + red[2][3];
    float F1 = red[3][0] + red[3][1] + red[3][2] + red[3][3];
    float F2 = red[4][0] + red[4][1] + red[4][2] + red[4][3];
    float* loc = out + (size_t)b * 52 + loff;
    loc[0 * dcnt + d] = L0;
    loc[1 * dcnt + d] = L1;
    float* cf = out + 6656 + (size_t)b * 78 + coff;
    cf[0 * dcnt + d] = F0;
    cf[1 * dcnt + d] = F1;
    cf[2 * dcnt + d] = F2;
  }
}

extern "C" void kernel_launch(void* const* d_in, const int* in_sizes, int n_in,
                              void* d_out, int out_size, void* d_ws, size_t ws_size,
                              hipStream_t stream) {
  (void)in_sizes; (void)n_in; (void)out_size;
  const float* x    = (const float*)d_in[0];
  const float* lw0  = (const float*)d_in[2];
  const float* cw0  = (const float*)d_in[3];
  const float* e0w1 = (const float*)d_in[4];
  const float* e0w2 = (const float*)d_in[5];
  const float* lw1  = (const float*)d_in[6];
  const float* cw1  = (const float*)d_in[7];
  const float* e1w1 = (const float*)d_in[8];
  const float* e1w2 = (const float*)d_in[9];
  const float* lw2  = (const float*)d_in[10];
  const float* cw2  = (const float*)d_in[11];
  const float* e2w1 = (const float*)d_in[12];
  const float* e2w2 = (const float*)d_in[13];
  const float* lw3  = (const float*)d_in[14];
  const float* cw3  = (const float*)d_in[15];
  float* out = (float*)d_out;
  bf16* W = (bf16*)d_ws;

  // element offsets (bf16)
  const size_t A0o  = 0;              // 8,388,608 (dead after GEMM1; reused for w2p in compact)
  const size_t W1o  = 8388608;        // W1c0 (1,048,576); later W1c1/W1c2/h3a/h3b
  const size_t h1ao = 9437184;        // 2,621,440 (padded)   -> later h2a
  const size_t h1bo = 12058624;       // 4,194,304            -> later h2b
  const size_t W1c1 = 8388608, W1c2 = 8650752, h3ao = 8716288, h3bo = 8978432;
  const size_t h2ao = 9437184, h2bo = 12058624;
  const bool big = ws_size >= (size_t)60817408;
  const size_t w2p0o = big ? (size_t)16252928 : (size_t)0;
  const size_t w2p1o = 0, w2p2o = 3538944;

  // zero padded h1a
  hipMemsetAsync(W + h1ao, 0, (size_t)2621440 * 2, stream);

  pack_x<<<dim3(128, 32), 256, 0, stream>>>(x, W + A0o);
  cvt_w1<<<512, 256, 0, stream>>>(e0w1, W + W1o, 131072);

  GP g1 = {W + A0o, W + W1o, W + h1ao, 2048,
           0, 2048, 0, 0, 0, 0,
           5, 20480, 7, 2048, 3, 512, 2048,
           9, 512, 0, 0};
  gemm_bf<2, 2, false><<<dim3(64, 8), 256, 0, stream>>>(g1);

  if (big) {
    pack_w2<<<dim3(1024, 8), 256, 0, stream>>>(e0w2, W + w2p0o, 0, 512);
    GP g2 = {W + h1ao, W + w2p0o, W + h1bo, 6144,
             3, 20480, 0, 0, 7, 2048,
             0, 4096, 0, 0, 0, 0, 0,
             10, 1024, 0, 9};
    gemm_bf<4, 4, true><<<dim3(8, 32), 256, 0, stream>>>(g2);
  } else {
    pack_w2<<<dim3(512, 8), 256, 0, stream>>>(e0w2, W + w2p0o, 0, 512);
    GP g2a = {W + h1ao, W + w2p0o, W + h1bo, 6144,
              3, 20480, 0, 0, 7, 2048,
              0, 4096, 0, 0, 0, 0, 0,
              9, 1024, 0, 9};
    gemm_bf<2, 2, true><<<dim3(16, 32), 256, 0, stream>>>(g2a);
    pack_w2<<<dim3(512, 8), 256, 0, stream>>>(e0w2, W + w2p0o, 512, 512);
    GP g2b = {W + h1ao, W + w2p0o, W + h1bo, 6144,
              3, 20480, 0, 0, 7, 2048,
              0, 4096, 0, 0, 0, 0, 0,
              9, 1024, 512, 9};
    gemm_bf<2, 2, true><<<dim3(16, 32), 256, 0, stream>>>(g2b);
  }

  // heads on h1b (before h1b region is reused for h2b)
  heads_k<bf16, false><<<128 * 7, 256, 0, stream>>>(
      W + h1bo, lw1, cw1, out, 1024, 7, 32768, 4096, 1024, 1, 30, 45);

  // layer 1
  hipMemsetAsync(W + h2ao, 0, (size_t)786432 * 2, stream);   // h1a dead now
  cvt_w1<<<128, 256, 0, stream>>>(e1w1, W + W1c1, 32768);
  GP g3 = {W + h1bo, W + W1c1, W + h2ao, 1024,
           4, 32768, 3, 8192, 3, 1024,
           4, 6144, 3, 1024, 3, 256, 1024,
           8, 256, 0, 0};
  gemm_bf<2, 2, false><<<dim3(32, 4), 256, 0, stream>>>(g3);
  pack_w2<<<dim3(512, 4), 256, 0, stream>>>(e1w2, W + w2p1o, 0, 256);
  GP g4 = {W + h2ao, W + w2p1o, W + h2bo, 3072,
           2, 6144, 0, 0, 3, 1024,
           0, 2048, 0, 0, 0, 0, 0,
           9, 512, 0, 8};
  gemm_bf<2, 2, true><<<dim3(8, 32), 256, 0, stream>>>(g4);
  heads_k<bf16, false><<<128 * 3, 256, 0, stream>>>(
      W + h2bo, lw2, cw2, out, 512, 3, 8192, 2048, 512, 1, 44, 66);

  // layer 2
  hipMemsetAsync(W + h3ao, 0, (size_t)262144 * 2, stream);
  cvt_w1<<<32, 256, 0, stream>>>(e2w1, W + W1c2, 8192);
  GP g5 = {W + h2bo, W + W1c2, W + h3ao, 512,
           3, 8192, 1, 4096, 3, 512,
           3, 2048, 1, 512, 3, 128, 512,
           7, 128, 0, 0};
  gemm_bf<2, 2, false><<<dim3(16, 2), 256, 0, stream>>>(g5);
  pack_w2<<<dim3(256, 2), 256, 0, stream>>>(e2w2, W + w2p2o, 0, 128);
  GP g6 = {W + h3ao, W + w2p2o, W + h3bo, 1536,
           1, 2048, 0, 0, 1, 512,
           0, 1024, 0, 0, 0, 0, 0,
           8, 256, 0, 7};
  gemm_bf<2, 2, true><<<dim3(4, 16), 256, 0, stream>>>(g6);
  heads_k<bf16, false><<<128 * 1, 256, 0, stream>>>(
      W + h3bo, lw3, cw3, out, 256, 1, 2048, 1024, 256, 1, 50, 75);

  // head 0 on x
  heads_k<float, true><<<128 * 15, 256, 0, stream>>>(
      x, lw0, cw0, out, 2048, 15, 131072, 4, 1, 64, 0, 0);
}

// Round 4
// 309.947 us; speedup vs baseline: 9.7274x; 1.2248x over previous
//
#include <hip/hip_runtime.h>

typedef __bf16 bf16;
typedef bf16 bf16x2 __attribute__((ext_vector_type(2)));
typedef bf16 bf16x8 __attribute__((ext_vector_type(8)));
typedef float f32x4 __attribute__((ext_vector_type(4)));

__device__ __forceinline__ void gload16(const bf16* g, bf16* l) {
  __builtin_amdgcn_global_load_lds((const __attribute__((address_space(1))) void*)g,
                                   (__attribute__((address_space(3))) void*)l, 16, 0, 0);
}

// ---------- pack x + fused head0 partials ----------
// x [128][2048][16][4] f32 -> A0 bf16 [4096][2048] (even d), plus per-(b,cb)
// head0 partial dot products into P [b*32+cb][5][15] f32.
__global__ __launch_bounds__(256) void pack_x_fused(const float* __restrict__ x,
                                                    bf16* __restrict__ A0,
                                                    const float* __restrict__ wl0,
                                                    const float* __restrict__ wc0,
                                                    float* __restrict__ P) {
  __shared__ float tile[64 * 65];
  const int b = blockIdx.x, cb = blockIdx.y;
  const int t = threadIdx.x;
  const float* src = x + ((size_t)b * 2048 + cb * 64) * 64;
  #pragma unroll
  for (int p = 0; p < 16; ++p) {
    int idx = t + p * 256;
    tile[(idx >> 6) * 65 + (idx & 63)] = src[idx];
  }
  __syncthreads();
  // A0 pack
  bf16* dst = A0 + ((size_t)b * 32) * 2048 + cb * 64;
  const int cl2 = (t & 31) * 2, mr0 = t >> 5;
  #pragma unroll
  for (int p = 0; p < 4; ++p) {
    int mrow = mr0 + p * 8;
    int dd = mrow >> 2, hw = mrow & 3;
    int sdhw = dd * 8 + hw;
    bf16x2 v;
    v.x = (bf16)tile[cl2 * 65 + sdhw];
    v.y = (bf16)tile[(cl2 + 1) * 65 + sdhw];
    *(bf16x2*)(dst + (size_t)mrow * 2048 + cl2) = v;
  }
  // head0 partials: wave wv owns d' in [wv*4, wv*4+dcnt)
  const int wv = t >> 6, lane = t & 63;
  const int dstart = wv * 4;
  const int dcnt = (wv == 3) ? 3 : 4;
  float acc[4][5] = {};
  #pragma unroll
  for (int i = 0; i < 8; ++i) {
    int idx = lane + i * 64;
    int c = idx >> 3, kdhw = idx & 7;
    int kd = kdhw >> 2, hw = kdhw & 3;
    int cg = cb * 64 + c;
    float w0 = wl0[cg * 8 + kdhw], w1 = wl0[16384 + cg * 8 + kdhw];
    float v0 = wc0[cg * 8 + kdhw], v1 = wc0[16384 + cg * 8 + kdhw],
          v2 = wc0[32768 + cg * 8 + kdhw];
    #pragma unroll
    for (int dd = 0; dd < 4; ++dd) {
      if (dd < dcnt) {
        float xv = tile[c * 65 + (dstart + dd + kd) * 4 + hw];
        acc[dd][0] += xv * w0; acc[dd][1] += xv * w1;
        acc[dd][2] += xv * v0; acc[dd][3] += xv * v1; acc[dd][4] += xv * v2;
      }
    }
  }
  #pragma unroll
  for (int dd = 0; dd < 4; ++dd)
    #pragma unroll
    for (int j = 0; j < 5; ++j)
      #pragma unroll
      for (int off = 32; off; off >>= 1)
        acc[dd][j] += __shfl_down(acc[dd][j], off, 64);
  if (lane == 0) {
    float* pp = P + ((size_t)(b * 32 + cb)) * 75;
    for (int dd = 0; dd < dcnt; ++dd)
      for (int j = 0; j < 5; ++j)
        pp[j * 15 + dstart + dd] = acc[dd][j];
  }
}

// ---------- head0 reduce: sum 32 cb-partials, scatter to out ----------
__global__ __launch_bounds__(128) void head0_reduce(const float* __restrict__ P,
                                                    float* __restrict__ out) {
  const int b = blockIdx.x, t = threadIdx.x;
  if (t < 75) {
    float s = 0.f;
    for (int cb = 0; cb < 32; ++cb) s += P[((size_t)(b * 32 + cb)) * 75 + t];
    int j = t / 15, d = t % 15;
    if (j < 2) out[b * 52 + j * 15 + d] = s;
    else       out[6656 + b * 78 + (j - 2) * 15 + d] = s;
  }
}

// ---------- f32 -> bf16 flat convert (n8 groups of 8) ----------
__global__ __launch_bounds__(256) void cvt_w1(const float* __restrict__ in, bf16* __restrict__ out, int n8) {
  int i = blockIdx.x * 256 + threadIdx.x;
  if (i < n8) {
    const float4* p = (const float4*)(in + (size_t)i * 8);
    float4 a = p[0], b = p[1];
    bf16x8 v = {(bf16)a.x, (bf16)a.y, (bf16)a.z, (bf16)a.w,
                (bf16)b.x, (bf16)b.y, (bf16)b.z, (bf16)b.w};
    *(bf16x8*)(out + (size_t)i * 8) = v;
  }
}

// ---------- w2 [cout][cin][27] f32 -> w2p [oCnt][27][cin] bf16 ----------
__global__ __launch_bounds__(256) void pack_w2(const float* __restrict__ w2, bf16* __restrict__ w2p,
                                               int oBase, int cin) {
  __shared__ float tile[64 * 27];
  const int orel = blockIdx.x, cb = blockIdx.y;
  const int o = oBase + orel;
  const float* src = w2 + ((size_t)o * cin + cb * 64) * 27;
  const int t = threadIdx.x;
  for (int idx = t; idx < 1728; idx += 256) tile[idx] = src[idx];
  __syncthreads();
  bf16* dst = w2p + (size_t)orel * 27 * cin + cb * 64;
  for (int idx = t; idx < 1728; idx += 256) {
    int tap = idx >> 6, cl = idx & 63;
    dst[(size_t)tap * cin + cl] = (bf16)tile[cl * 27 + tap];
  }
}

// ---------- bf16 MFMA GEMM ----------
struct GP {
  const bf16* A; const bf16* B; bf16* O;
  int K;
  int ashb, asB, am1, as1, am2, as2;                 // A row base decompose
  int oshb, osB, om1, os1, om2, os2, oOff;           // out row base decompose
  int lgCv, coutS, oCol0, lgCin;                     // out col map / w2p mode
};

template <int FM, int FN, bool W2M>
__global__ __launch_bounds__(256) void gemm_bf(GP p) {
  constexpr int BM = FM * 32, BN = FN * 32;
  __shared__ bf16 lds[(BM + BN) * 64];
  bf16* ldsA = lds;
  bf16* ldsB = lds + BM * 64;
  const int tid = threadIdx.x;
  const int bm = blockIdx.x, bn = blockIdx.y;

  int aBase[BM / 32], aL[BM / 32];
  #pragma unroll
  for (int q = 0; q < BM / 32; ++q) {
    int idx = tid + q * 256;
    int row = idx >> 3, cg = idx & 7;
    int m = bm * BM + row;
    aBase[q] = (m >> p.ashb) * p.asB + ((m >> 2) & p.am1) * p.as1 + (m & p.am2) * p.as2;
    aL[q] = (cg ^ (row & 7)) * 8;
  }
  int bN[BN / 32], bL[BN / 32];
  #pragma unroll
  for (int q = 0; q < BN / 32; ++q) {
    int idx = tid + q * 256;
    int row = idx >> 3, cg = idx & 7;
    bN[q] = bn * BN + row;
    bL[q] = (cg ^ (row & 7)) * 8;
  }

  const int wv = tid >> 6, wm = wv >> 1, wn = wv & 1;
  const int lane = tid & 63, r = lane & 15, g = lane >> 4;

  f32x4 acc[FM][FN];
  const f32x4 zz = {0.f, 0.f, 0.f, 0.f};
  #pragma unroll
  for (int i = 0; i < FM; ++i)
    #pragma unroll
    for (int j = 0; j < FN; ++j) acc[i][j] = zz;

  for (int k0 = 0; k0 < p.K; k0 += 64) {
    #pragma unroll
    for (int q = 0; q < BM / 32; ++q) {
      int idx = tid + q * 256;
      gload16(p.A + aBase[q] + k0 + aL[q], ldsA + idx * 8);
    }
    if (W2M) {
      const int kd = k0 >> (p.lgCin + 2);
      const int hw = (k0 >> p.lgCin) & 3;
      const int c0 = k0 & ((1 << p.lgCin) - 1);
      #pragma unroll
      for (int q = 0; q < BN / 32; ++q) {
        int n = bN[q];
        int op = n & ((1 << p.lgCv) - 1);
        int hwp = n >> p.lgCv;
        int kh = 1 + (hw >> 1) - (hwp >> 1);
        int kw = 1 + (hw & 1) - (hwp & 1);
        int src = ((op * 27 + kd * 9 + kh * 3 + kw) << p.lgCin) + c0 + bL[q];
        int idx = tid + q * 256;
        gload16(p.B + src, ldsB + idx * 8);
      }
    } else {
      #pragma unroll
      for (int q = 0; q < BN / 32; ++q) {
        int idx = tid + q * 256;
        gload16(p.B + (size_t)bN[q] * p.K + k0 + bL[q], ldsB + idx * 8);
      }
    }
    __syncthreads();
    #pragma unroll
    for (int ks = 0; ks < 2; ++ks) {
      bf16x8 af[FM], bfr[FN];
      #pragma unroll
      for (int i = 0; i < FM; ++i) {
        int row = wm * FM * 16 + i * 16 + r;
        int pcg = (ks * 4 + g) ^ (row & 7);
        af[i] = *(const bf16x8*)(ldsA + row * 64 + pcg * 8);
      }
      #pragma unroll
      for (int j = 0; j < FN; ++j) {
        int row = wn * FN * 16 + j * 16 + r;
        int pcg = (ks * 4 + g) ^ (row & 7);
        bfr[j] = *(const bf16x8*)(ldsB + row * 64 + pcg * 8);
      }
      #pragma unroll
      for (int i = 0; i < FM; ++i)
        #pragma unroll
        for (int j = 0; j < FN; ++j)
          acc[i][j] = __builtin_amdgcn_mfma_f32_16x16x32_bf16(af[i], bfr[j], acc[i][j], 0, 0, 0);
    }
    __syncthreads();
  }

  #pragma unroll
  for (int i = 0; i < FM; ++i) {
    #pragma unroll
    for (int j = 0; j < FN; ++j) {
      int ncol = bn * BN + wn * FN * 16 + j * 16 + r;
      int outcol = (ncol >> p.lgCv) * p.coutS + p.oCol0 + (ncol & ((1 << p.lgCv) - 1));
      #pragma unroll
      for (int jr = 0; jr < 4; ++jr) {
        int m = bm * BM + wm * FM * 16 + i * 16 + g * 4 + jr;
        int oa = (m >> p.oshb) * p.osB + ((m >> 2) & p.om1) * p.os1 + (m & p.om2) * p.os2 + p.oOff + outcol;
        p.O[oa] = (bf16)acc[i][j][jr];
      }
    }
  }
}

// ---------- detection heads: kernel (2,2,2) VALID (channel-last bf16) ----------
__global__ __launch_bounds__(256)
void heads_k(const bf16* __restrict__ in, const float* __restrict__ wl,
             const float* __restrict__ wc, float* __restrict__ out,
             const int C, const int dcnt, const int sB, const int sD,
             const int sHW, const int loff, const int coff) {
  const int tid = threadIdx.x;
  const int blk = blockIdx.x;
  const int b = blk / dcnt, d = blk - b * dcnt;
  float a0 = 0, a1 = 0, c0 = 0, c1 = 0, c2 = 0;
  const int C8 = C * 8;
  for (int c = tid; c < C; c += 256) {
    #pragma unroll
    for (int kd = 0; kd < 2; ++kd) {
      #pragma unroll
      for (int hw = 0; hw < 4; ++hw) {
        const float v = (float)in[b * sB + (d + kd) * sD + hw * sHW + c];
        const int wi = c * 8 + kd * 4 + hw;
        a0 += v * wl[wi];  a1 += v * wl[C8 + wi];
        c0 += v * wc[wi];  c1 += v * wc[C8 + wi];  c2 += v * wc[2 * C8 + wi];
      }
    }
  }
  #pragma unroll
  for (int off = 32; off; off >>= 1) {
    a0 += __shfl_down(a0, off, 64);
    a1 += __shfl_down(a1, off, 64);
    c0 += __shfl_down(c0, off, 64);
    c1 += __shfl_down(c1, off, 64);
    c2 += __shfl_down(c2, off, 64);
  }
  __shared__ float red[5][4];
  const int lane = tid & 63, wv = tid >> 6;
  if (lane == 0) { red[0][wv] = a0; red[1][wv] = a1; red[2][wv] = c0; red[3][wv] = c1; red[4][wv] = c2; }
  __syncthreads();
  if (tid == 0) {
    float L0 = red[0][0] + red[0][1] + red[0][2] + red[0][3];
    float L1 = red[1][0] + red[1][1] + red[1][2] + red[1][3];
    float F0 = red[2][0] + red[2][1] + red[2][2] + red[2][3];
    float F1 = red[3][0] + red[3][1] + red[3][2] + red[3][3];
    float F2 = red[4][0] + red[4][1] + red[4][2] + red[4][3];
    float* loc = out + (size_t)b * 52 + loff;
    loc[0 * dcnt + d] = L0;
    loc[1 * dcnt + d] = L1;
    float* cf = out + 6656 + (size_t)b * 78 + coff;
    cf[0 * dcnt + d] = F0;
    cf[1 * dcnt + d] = F1;
    cf[2 * dcnt + d] = F2;
  }
}

extern "C" void kernel_launch(void* const* d_in, const int* in_sizes, int n_in,
                              void* d_out, int out_size, void* d_ws, size_t ws_size,
                              hipStream_t stream) {
  (void)in_sizes; (void)n_in; (void)out_size;
  const float* x    = (const float*)d_in[0];
  const float* lw0  = (const float*)d_in[2];
  const float* cw0  = (const float*)d_in[3];
  const float* e0w1 = (const float*)d_in[4];
  const float* e0w2 = (const float*)d_in[5];
  const float* lw1  = (const float*)d_in[6];
  const float* cw1  = (const float*)d_in[7];
  const float* e1w1 = (const float*)d_in[8];
  const float* e1w2 = (const float*)d_in[9];
  const float* lw2  = (const float*)d_in[10];
  const float* cw2  = (const float*)d_in[11];
  const float* e2w1 = (const float*)d_in[12];
  const float* e2w2 = (const float*)d_in[13];
  const float* lw3  = (const float*)d_in[14];
  const float* cw3  = (const float*)d_in[15];
  float* out = (float*)d_out;
  bf16* W = (bf16*)d_ws;

  // element offsets (bf16)
  const size_t A0o  = 0;              // 8,388,608 (dead after GEMM1; reused for w2p in compact)
  const size_t W1o  = 8388608;        // W1c0 (1,048,576); later W1c1/W1c2/h3a/h3b
  const size_t h1ao = 9437184;        // 2,621,440 (padded)   -> later h2a
  const size_t h1bo = 12058624;       // 4,194,304            -> later h2b
  const size_t W1c1 = 8388608, W1c2 = 8650752, h3ao = 8716288, h3bo = 8978432;
  const size_t h2ao = 9437184, h2bo = 12058624;
  const bool big = ws_size >= (size_t)60817408;
  const size_t w2p0o = big ? (size_t)16252928 : (size_t)0;
  const size_t w2p1o = 0, w2p2o = 3538944;
  float* P = (float*)(W + h1bo);      // 307,200 f32 head0 partials (h1b not yet live)

  // zero padded h1a
  hipMemsetAsync(W + h1ao, 0, (size_t)2621440 * 2, stream);

  pack_x_fused<<<dim3(128, 32), 256, 0, stream>>>(x, W + A0o, lw0, cw0, P);
  head0_reduce<<<128, 128, 0, stream>>>(P, out);
  cvt_w1<<<512, 256, 0, stream>>>(e0w1, W + W1o, 131072);

  GP g1 = {W + A0o, W + W1o, W + h1ao, 2048,
           0, 2048, 0, 0, 0, 0,
           5, 20480, 7, 2048, 3, 512, 2048,
           9, 512, 0, 0};
  gemm_bf<2, 2, false><<<dim3(64, 8), 256, 0, stream>>>(g1);

  if (big) {
    pack_w2<<<dim3(1024, 8), 256, 0, stream>>>(e0w2, W + w2p0o, 0, 512);
    GP g2 = {W + h1ao, W + w2p0o, W + h1bo, 6144,
             3, 20480, 0, 0, 7, 2048,
             0, 4096, 0, 0, 0, 0, 0,
             10, 1024, 0, 9};
    gemm_bf<2, 2, true><<<dim3(16, 64), 256, 0, stream>>>(g2);
  } else {
    pack_w2<<<dim3(512, 8), 256, 0, stream>>>(e0w2, W + w2p0o, 0, 512);
    GP g2a = {W + h1ao, W + w2p0o, W + h1bo, 6144,
              3, 20480, 0, 0, 7, 2048,
              0, 4096, 0, 0, 0, 0, 0,
              9, 1024, 0, 9};
    gemm_bf<2, 2, true><<<dim3(16, 32), 256, 0, stream>>>(g2a);
    pack_w2<<<dim3(512, 8), 256, 0, stream>>>(e0w2, W + w2p0o, 512, 512);
    GP g2b = {W + h1ao, W + w2p0o, W + h1bo, 6144,
              3, 20480, 0, 0, 7, 2048,
              0, 4096, 0, 0, 0, 0, 0,
              9, 1024, 512, 9};
    gemm_bf<2, 2, true><<<dim3(16, 32), 256, 0, stream>>>(g2b);
  }

  // heads on h1b (before h1b region is reused for h2b)
  heads_k<<<128 * 7, 256, 0, stream>>>(
      W + h1bo, lw1, cw1, out, 1024, 7, 32768, 4096, 1024, 30, 45);

  // layer 1
  hipMemsetAsync(W + h2ao, 0, (size_t)786432 * 2, stream);   // h1a dead now
  cvt_w1<<<128, 256, 0, stream>>>(e1w1, W + W1c1, 32768);
  GP g3 = {W + h1bo, W + W1c1, W + h2ao, 1024,
           4, 32768, 3, 8192, 3, 1024,
           4, 6144, 3, 1024, 3, 256, 1024,
           8, 256, 0, 0};
  gemm_bf<1, 1, false><<<dim3(64, 8), 256, 0, stream>>>(g3);
  pack_w2<<<dim3(512, 4), 256, 0, stream>>>(e1w2, W + w2p1o, 0, 256);
  GP g4 = {W + h2ao, W + w2p1o, W + h2bo, 3072,
           2, 6144, 0, 0, 3, 1024,
           0, 2048, 0, 0, 0, 0, 0,
           9, 512, 0, 8};
  gemm_bf<1, 1, true><<<dim3(16, 64), 256, 0, stream>>>(g4);
  heads_k<<<128 * 3, 256, 0, stream>>>(
      W + h2bo, lw2, cw2, out, 512, 3, 8192, 2048, 512, 44, 66);

  // layer 2
  hipMemsetAsync(W + h3ao, 0, (size_t)262144 * 2, stream);
  cvt_w1<<<32, 256, 0, stream>>>(e2w1, W + W1c2, 8192);
  GP g5 = {W + h2bo, W + W1c2, W + h3ao, 512,
           3, 8192, 1, 4096, 3, 512,
           3, 2048, 1, 512, 3, 128, 512,
           7, 128, 0, 0};
  gemm_bf<1, 1, false><<<dim3(32, 4), 256, 0, stream>>>(g5);
  pack_w2<<<dim3(256, 2), 256, 0, stream>>>(e2w2, W + w2p2o, 0, 128);
  GP g6 = {W + h3ao, W + w2p2o, W + h3bo, 1536,
           1, 2048, 0, 0, 1, 512,
           0, 1024, 0, 0, 0, 0, 0,
           8, 256, 0, 7};
  gemm_bf<1, 1, true><<<dim3(8, 32), 256, 0, stream>>>(g6);
  heads_k<<<128 * 1, 256, 0, stream>>>(
      W + h3bo, lw3, cw3, out, 256, 1, 2048, 1024, 256, 50, 75);
}